// Round 4
// baseline (664.555 us; speedup 1.0000x reference)
//
#include <hip/hip_runtime.h>

#define BB 256
#define LL 65536
#define TS 1024
#define HIST 256
#define WINW 64
#define DIM 256
#define NPAT 64

typedef short s8v __attribute__((ext_vector_type(8)));
typedef float f4v __attribute__((ext_vector_type(4)));

#define MFMA16(a, b, c) __builtin_amdgcn_mfma_f32_16x16x32_bf16((a), (b), (c), 0, 0, 0)
#define LOG2E 1.44269504f

// ---- fp32 -> bf16 hi/lo split (combined error ~2^-18 relative) ----
__device__ __forceinline__ short bf16rne(float f) {
    unsigned u = __float_as_uint(f);
    unsigned r = (u + 0x7fffu + ((u >> 16) & 1u)) >> 16;
    return (short)r;
}
__device__ __forceinline__ float bf16tof(short h) {
    return __uint_as_float(((unsigned)(unsigned short)h) << 16);
}
__device__ __forceinline__ void split2(float f, short& hi, short& lo) {
    hi = bf16rne(f);
    lo = bf16rne(f - bf16tof(hi));
}

// ---- prep: conv_w[d][h] -> wF[kt*4+q][d][j] (B-frag layout, k=h, n=d), hi/lo ----
__global__ void prep_wf(const float* __restrict__ w, short* __restrict__ wFH,
                        short* __restrict__ wFL) {
    int idx = blockIdx.x * 256 + threadIdx.x;     // 8192 = 32 qk * 256 d
    int d = idx & 255, qk = idx >> 8;
    int h0 = qk * 8;
    s8v hv, lv;
#pragma unroll
    for (int j = 0; j < 8; ++j) {
        short h, l; split2(w[d * HIST + h0 + j], h, l);
        hv[j] = h; lv[j] = l;
    }
    *(s8v*)(wFH + (size_t)idx * 8) = hv;
    *(s8v*)(wFL + (size_t)idx * 8) = lv;
}

// ---- prep: keys[d][p] -> kF[kt*4+q][p][j] (k=d, n=p), hi/lo ----
__global__ void prep_keysf(const float* __restrict__ keys, short* __restrict__ kFH,
                           short* __restrict__ kFL) {
    int idx = blockIdx.x * 256 + threadIdx.x;     // 2048 = 32 qk * 64 p
    int p = idx & 63, qk = idx >> 6;
    int d0 = qk * 8;
    s8v hv, lv;
#pragma unroll
    for (int j = 0; j < 8; ++j) {
        short h, l; split2(keys[(d0 + j) * NPAT + p], h, l);
        hv[j] = h; lv[j] = l;
    }
    *(s8v*)(kFH + (size_t)idx * 8) = hv;
    *(s8v*)(kFL + (size_t)idx * 8) = lv;
}

// ---- prep: shapes[p][w] -> sF[kt*4+q][w][j] (k=p, n=w), hi/lo ----
__global__ void prep_shapesf(const float* __restrict__ sh, short* __restrict__ sFH,
                             short* __restrict__ sFL) {
    int idx = blockIdx.x * 256 + threadIdx.x;     // 512 = 8 qk * 64 w
    int w = idx & 63, qk = idx >> 6;
    int p0 = qk * 8;
    s8v hv, lv;
#pragma unroll
    for (int j = 0; j < 8; ++j) {
        short h, l; split2(sh[(p0 + j) * WINW + w], h, l);
        hv[j] = h; lv[j] = l;
    }
    *(s8v*)(sFH + (size_t)idx * 8) = hv;
    *(s8v*)(sFL + (size_t)idx * 8) = lv;
}

#define WELEM 2240           // 31*64 + 256 window elements
#define WUNIT 280            // WELEM/8
#define HPAD 264             // hid row stride (256 + 8)

__device__ __forceinline__ int swz(int u) { return u ^ ((u >> 3) & 7); }

// ---- fused conv + relu + (hid @ keys) + relu6 (scores stored pre-scaled by log2e) ----
// block = (32 timesteps, one batch); 256 threads = 4 waves. ~3 blocks/CU (LDS-capped).
__launch_bounds__(256, 3)
__global__ void scores_mfma(const float* __restrict__ x,
                            const short* __restrict__ wFH, const short* __restrict__ wFL,
                            const short* __restrict__ kFH, const short* __restrict__ kFL,
                            const float* __restrict__ conv_b,
                            float* __restrict__ scores) {
    __shared__ __align__(16) short xsH[WUNIT * 8], xsL[WUNIT * 8];
    __shared__ __align__(16) short hidH[32 * HPAD], hidL[32 * HPAD];

    const int b = blockIdx.y, t0 = blockIdx.x * 32;
    const int tid = threadIdx.x;
    const int lane = tid & 63, wid = tid >> 6;
    const int m = lane & 15, q = lane >> 4;

    // Stage x window as swizzled bf16 hi/lo. A[row][k] = x[t0*64-255 + row*64 + k]
    const float* xb = x + (size_t)b * LL;
    const int gbase = t0 * WINW - (HIST - 1);
    for (int i = tid; i < WELEM; i += 256) {
        int gi = gbase + i;
        float v = (gi >= 0) ? xb[gi] : 0.0f;
        short h, l; split2(v, h, l);
        int pos = (swz(i >> 3) << 3) | (i & 7);
        xsH[pos] = h; xsL[pos] = l;
    }
    __syncthreads();

    // Phase 1: conv GEMM. Wave wid owns d-range [wid*64, +64). B dbuf-prefetched.
    const int nb = wid * 64;
    f4v acc[2][4];
#pragma unroll
    for (int mt = 0; mt < 2; ++mt)
#pragma unroll
        for (int nt = 0; nt < 4; ++nt) acc[mt][nt] = (f4v)0.0f;

    s8v bH[2][4], bL[2][4];
#pragma unroll
    for (int nt = 0; nt < 4; ++nt) {
        size_t bi = ((size_t)q * 256 + nb + nt * 16 + m) * 8;
        bH[0][nt] = *(const s8v*)(wFH + bi);
        bL[0][nt] = *(const s8v*)(wFL + bi);
    }
#pragma unroll
    for (int kt = 0; kt < 8; ++kt) {
        const int cur = kt & 1, nxt = cur ^ 1;
        if (kt < 7) {
#pragma unroll
            for (int nt = 0; nt < 4; ++nt) {
                size_t bi = ((size_t)((kt + 1) * 4 + q) * 256 + nb + nt * 16 + m) * 8;
                bH[nxt][nt] = *(const s8v*)(wFH + bi);
                bL[nxt][nt] = *(const s8v*)(wFL + bi);
            }
        }
        s8v aH[2], aL[2];
#pragma unroll
        for (int mt = 0; mt < 2; ++mt) {
            int row = mt * 16 + m;
            int su = swz(row * 8 + kt * 4 + q) << 3;
            aH[mt] = *(const s8v*)&xsH[su];
            aL[mt] = *(const s8v*)&xsL[su];
        }
#pragma unroll
        for (int mt = 0; mt < 2; ++mt)
#pragma unroll
            for (int nt = 0; nt < 4; ++nt) {
                acc[mt][nt] = MFMA16(aH[mt], bH[cur][nt], acc[mt][nt]);
                acc[mt][nt] = MFMA16(aL[mt], bH[cur][nt], acc[mt][nt]);
                acc[mt][nt] = MFMA16(aH[mt], bL[cur][nt], acc[mt][nt]);
            }
    }

    // Epilogue 1: bias + relu -> hid (bf16 hi/lo, padded rows)
#pragma unroll
    for (int mt = 0; mt < 2; ++mt)
#pragma unroll
        for (int nt = 0; nt < 4; ++nt) {
            int d = nb + nt * 16 + m;
            float bias = conv_b[d];
#pragma unroll
            for (int r = 0; r < 4; ++r) {
                int row = mt * 16 + q * 4 + r;
                float v = fmaxf(acc[mt][nt][r] + bias, 0.0f);
                short h, l; split2(v, h, l);
                hidH[row * HPAD + d] = h;
                hidL[row * HPAD + d] = l;
            }
        }
    __syncthreads();

    // Phase 2: scores GEMM (K=256 over d). Wave wid owns p-range [wid*16, +16).
    const int pb = wid * 16;
    f4v acc2[2];
    acc2[0] = (f4v)0.0f; acc2[1] = (f4v)0.0f;
    s8v kbH[2], kbL[2];
    {
        size_t bi = ((size_t)q * 64 + pb + m) * 8;
        kbH[0] = *(const s8v*)(kFH + bi);
        kbL[0] = *(const s8v*)(kFL + bi);
    }
#pragma unroll
    for (int kt = 0; kt < 8; ++kt) {
        const int cur = kt & 1, nxt = cur ^ 1;
        if (kt < 7) {
            size_t bi = ((size_t)((kt + 1) * 4 + q) * 64 + pb + m) * 8;
            kbH[nxt] = *(const s8v*)(kFH + bi);
            kbL[nxt] = *(const s8v*)(kFL + bi);
        }
        s8v aH[2], aL[2];
#pragma unroll
        for (int mt = 0; mt < 2; ++mt) {
            int off = (mt * 16 + m) * HPAD + kt * 32 + q * 8;
            aH[mt] = *(const s8v*)&hidH[off];
            aL[mt] = *(const s8v*)&hidL[off];
        }
#pragma unroll
        for (int mt = 0; mt < 2; ++mt) {
            acc2[mt] = MFMA16(aH[mt], kbH[cur], acc2[mt]);
            acc2[mt] = MFMA16(aL[mt], kbH[cur], acc2[mt]);
            acc2[mt] = MFMA16(aH[mt], kbL[cur], acc2[mt]);
        }
    }
#pragma unroll
    for (int mt = 0; mt < 2; ++mt)
#pragma unroll
        for (int r = 0; r < 4; ++r) {
            int row = mt * 16 + q * 4 + r;
            float s = fminf(fmaxf(acc2[mt][r], 0.0f), 6.0f) * LOG2E;  // pre-scaled
            scores[((size_t)b * TS + t0 + row) * NPAT + pb + m] = s;
        }
}

// ---- sequential softmax scan, DPP reduction + 16-deep register prefetch ----
template <int CTRL>
__device__ __forceinline__ float dppadd(float x) {
    int t = __builtin_amdgcn_update_dpp(0, __float_as_int(x), CTRL, 0xf, 0xf, true);
    return x + __int_as_float(t);
}

#define PF 16

__launch_bounds__(64)
__global__ void scan_kernel(const float* __restrict__ scores,  // pre-scaled by log2e
                            const float* __restrict__ avg0,
                            float* __restrict__ probs) {
    const int b = blockIdx.x, p = threadIdx.x;
    float avgc = avg0[b * NPAT + p] * LOG2E;       // track avg*log2e
    const float invc = LOG2E / NPAT;
    const float* sc = scores + (size_t)b * TS * NPAT + p;
    float* pr = probs + (size_t)b * TS * NPAT + p;

    float sbuf[PF];
#pragma unroll
    for (int j = 0; j < PF; ++j) sbuf[j] = sc[(size_t)j * NPAT];

    for (int t0 = 0; t0 < TS; t0 += PF) {
#pragma unroll
        for (int j = 0; j < PF; ++j) {
            const int t = t0 + j;
            float z = sbuf[j] - avgc;              // = log2e*(s - avg)
            if (t + PF < TS) sbuf[j] = sc[(size_t)(t + PF) * NPAT];  // deep prefetch
            z = fminf(fmaxf(z, -115.0f), 115.0f);  // safety, never binds
            float e = exp2f(z);
            float v = e;                           // wave64 sum -> lane 63
            v = dppadd<0x111>(v);   // row_shr:1
            v = dppadd<0x112>(v);   // row_shr:2
            v = dppadd<0x114>(v);   // row_shr:4
            v = dppadd<0x118>(v);   // row_shr:8
            v = dppadd<0x142>(v);   // row_bcast:15
            v = dppadd<0x143>(v);   // row_bcast:31
            float tot = __int_as_float(__builtin_amdgcn_readlane(__float_as_int(v), 63));
            float prob = e * __builtin_amdgcn_rcpf(tot);
            pr[(size_t)t * NPAT] = prob;
            avgc = __builtin_fmaf(prob, LOG2E, avgc - invc);
        }
    }
}

// ---- signal = probs @ shapes (MFMA split-bf16), out = relu(signal - x) ----
__launch_bounds__(256)
__global__ void signal_mfma(const float* __restrict__ probs,
                            const short* __restrict__ sFH, const short* __restrict__ sFL,
                            const float* __restrict__ x,
                            float* __restrict__ out) {
    __shared__ __align__(16) short pH[64 * 72], pL[64 * 72];   // 72 = 64 + 8 pad
    const int b = blockIdx.y, t0 = blockIdx.x * 64;
    const int tid = threadIdx.x;
    const int lane = tid & 63, wid = tid >> 6;
    const int m = lane & 15, q = lane >> 4;

    const float* pbase = probs + ((size_t)b * TS + t0) * NPAT;
    for (int i = tid; i < 64 * 64; i += 256) {
        int r = i >> 6, c = i & 63;
        short h, l; split2(pbase[i], h, l);
        pH[r * 72 + c] = h; pL[r * 72 + c] = l;
    }
    __syncthreads();

    f4v acc[4];
#pragma unroll
    for (int nt = 0; nt < 4; ++nt) acc[nt] = (f4v)0.0f;

#pragma unroll
    for (int kt = 0; kt < 2; ++kt) {
        int off = (wid * 16 + m) * 72 + kt * 32 + q * 8;
        s8v aH = *(const s8v*)&pH[off];
        s8v aL = *(const s8v*)&pL[off];
#pragma unroll
        for (int nt = 0; nt < 4; ++nt) {
            size_t bi = ((size_t)(kt * 4 + q) * 64 + nt * 16 + m) * 8;
            s8v bH = *(const s8v*)(sFH + bi);
            s8v bL = *(const s8v*)(sFL + bi);
            acc[nt] = MFMA16(aH, bH, acc[nt]);
            acc[nt] = MFMA16(aL, bH, acc[nt]);
            acc[nt] = MFMA16(aH, bL, acc[nt]);
        }
    }
#pragma unroll
    for (int nt = 0; nt < 4; ++nt)
#pragma unroll
        for (int r = 0; r < 4; ++r) {
            int row = wid * 16 + q * 4 + r;
            int w = nt * 16 + m;
            size_t gi = (size_t)b * LL + (size_t)(t0 + row) * WINW + w;
            out[gi] = fmaxf(acc[nt][r] - x[gi], 0.0f);
        }
}

extern "C" void kernel_launch(void* const* d_in, const int* in_sizes, int n_in,
                              void* d_out, int out_size, void* d_ws, size_t ws_size,
                              hipStream_t stream) {
    const float* x      = (const float*)d_in[0];
    const float* avg0   = (const float*)d_in[1];
    const float* conv_w = (const float*)d_in[2];
    const float* conv_b = (const float*)d_in[3];
    const float* keys   = (const float*)d_in[4];
    const float* shapes = (const float*)d_in[5];
    float* out = (float*)d_out;

    char* ws = (char*)d_ws;
    size_t o = 0;
    float* scores = (float*)(ws + o); o += (size_t)BB * TS * NPAT * 4;   // 64 MB
    float* probs  = (float*)(ws + o); o += (size_t)BB * TS * NPAT * 4;   // 64 MB
    short* wFH = (short*)(ws + o); o += 8192 * 16;
    short* wFL = (short*)(ws + o); o += 8192 * 16;
    short* kFH = (short*)(ws + o); o += 2048 * 16;
    short* kFL = (short*)(ws + o); o += 2048 * 16;
    short* sFH = (short*)(ws + o); o += 512 * 16;
    short* sFL = (short*)(ws + o); o += 512 * 16;

    prep_wf<<<32, 256, 0, stream>>>(conv_w, wFH, wFL);
    prep_keysf<<<8, 256, 0, stream>>>(keys, kFH, kFL);
    prep_shapesf<<<2, 256, 0, stream>>>(shapes, sFH, sFL);

    scores_mfma<<<dim3(TS / 32, BB), 256, 0, stream>>>(x, wFH, wFL, kFH, kFL, conv_b, scores);
    scan_kernel<<<dim3(BB), 64, 0, stream>>>(scores, avg0, probs);
    signal_mfma<<<dim3(TS / 64, BB), 256, 0, stream>>>(probs, sFH, sFL, x, out);
}

// Round 5
// 476.607 us; speedup vs baseline: 1.3943x; 1.3943x over previous
//
#include <hip/hip_runtime.h>

#define BB 256
#define LL 65536
#define TS 1024
#define HIST 256
#define WINW 64
#define DIM 256
#define NPAT 64

typedef short s8v __attribute__((ext_vector_type(8)));
typedef float f4v __attribute__((ext_vector_type(4)));

#define MFMA16(a, b, c) __builtin_amdgcn_mfma_f32_16x16x32_bf16((a), (b), (c), 0, 0, 0)
#define LOG2E 1.44269504f

// ---- fp32 -> bf16 hi/lo split (combined error ~2^-18 relative) ----
__device__ __forceinline__ short bf16rne(float f) {
    unsigned u = __float_as_uint(f);
    unsigned r = (u + 0x7fffu + ((u >> 16) & 1u)) >> 16;
    return (short)r;
}
__device__ __forceinline__ float bf16tof(short h) {
    return __uint_as_float(((unsigned)(unsigned short)h) << 16);
}
__device__ __forceinline__ void split2(float f, short& hi, short& lo) {
    hi = bf16rne(f);
    lo = bf16rne(f - bf16tof(hi));
}

// ---- prep: conv_w[d][h] -> wF[kt*4+q][d][j] (B-frag layout, k=h, n=d), hi/lo ----
__global__ void prep_wf(const float* __restrict__ w, short* __restrict__ wFH,
                        short* __restrict__ wFL) {
    int idx = blockIdx.x * 256 + threadIdx.x;     // 8192 = 32 qk * 256 d
    int d = idx & 255, qk = idx >> 8;
    int h0 = qk * 8;
    s8v hv, lv;
#pragma unroll
    for (int j = 0; j < 8; ++j) {
        short h, l; split2(w[d * HIST + h0 + j], h, l);
        hv[j] = h; lv[j] = l;
    }
    *(s8v*)(wFH + (size_t)idx * 8) = hv;
    *(s8v*)(wFL + (size_t)idx * 8) = lv;
}

// ---- prep: keys[d][p] -> kF[kt*4+q][p][j] (k=d, n=p), hi/lo ----
__global__ void prep_keysf(const float* __restrict__ keys, short* __restrict__ kFH,
                           short* __restrict__ kFL) {
    int idx = blockIdx.x * 256 + threadIdx.x;     // 2048 = 32 qk * 64 p
    int p = idx & 63, qk = idx >> 6;
    int d0 = qk * 8;
    s8v hv, lv;
#pragma unroll
    for (int j = 0; j < 8; ++j) {
        short h, l; split2(keys[(d0 + j) * NPAT + p], h, l);
        hv[j] = h; lv[j] = l;
    }
    *(s8v*)(kFH + (size_t)idx * 8) = hv;
    *(s8v*)(kFL + (size_t)idx * 8) = lv;
}

// ---- prep: shapes[p][w] -> sF[kt*4+q][w][j] (k=p, n=w), hi/lo ----
__global__ void prep_shapesf(const float* __restrict__ sh, short* __restrict__ sFH,
                             short* __restrict__ sFL) {
    int idx = blockIdx.x * 256 + threadIdx.x;     // 512 = 8 qk * 64 w
    int w = idx & 63, qk = idx >> 6;
    int p0 = qk * 8;
    s8v hv, lv;
#pragma unroll
    for (int j = 0; j < 8; ++j) {
        short h, l; split2(sh[(p0 + j) * WINW + w], h, l);
        hv[j] = h; lv[j] = l;
    }
    *(s8v*)(sFH + (size_t)idx * 8) = hv;
    *(s8v*)(sFL + (size_t)idx * 8) = lv;
}

#define WELEM 2240           // 31*64 + 256 window elements
#define WUNIT 280            // WELEM/8
#define HPAD 264             // hid row stride (256 + 8)

__device__ __forceinline__ int swz(int u) { return u ^ ((u >> 3) & 7); }

// ---- fused conv + relu + (hid @ keys) + relu6 (scores stored pre-scaled by log2e) ----
// block = (32 timesteps, one batch); 256 threads = 4 waves.  [R3-known-good structure]
__launch_bounds__(256, 2)
__global__ void scores_mfma(const float* __restrict__ x,
                            const short* __restrict__ wFH, const short* __restrict__ wFL,
                            const short* __restrict__ kFH, const short* __restrict__ kFL,
                            const float* __restrict__ conv_b,
                            float* __restrict__ scores) {
    __shared__ __align__(16) short xsH[WUNIT * 8], xsL[WUNIT * 8];
    __shared__ __align__(16) short hidH[32 * HPAD], hidL[32 * HPAD];

    const int b = blockIdx.y, t0 = blockIdx.x * 32;
    const int tid = threadIdx.x;
    const int lane = tid & 63, wid = tid >> 6;
    const int m = lane & 15, q = lane >> 4;

    const float* xb = x + (size_t)b * LL;
    const int gbase = t0 * WINW - (HIST - 1);
    for (int i = tid; i < WELEM; i += 256) {
        int gi = gbase + i;
        float v = (gi >= 0) ? xb[gi] : 0.0f;
        short h, l; split2(v, h, l);
        int pos = (swz(i >> 3) << 3) | (i & 7);
        xsH[pos] = h; xsL[pos] = l;
    }
    __syncthreads();

    // Phase 1: conv GEMM. Wave wid owns d-range [wid*64, +64).
    const int nb = wid * 64;
    f4v acc[2][4];
#pragma unroll
    for (int mt = 0; mt < 2; ++mt)
#pragma unroll
        for (int nt = 0; nt < 4; ++nt) acc[mt][nt] = (f4v)0.0f;

    for (int kt = 0; kt < 8; ++kt) {
        s8v aH[2], aL[2];
#pragma unroll
        for (int mt = 0; mt < 2; ++mt) {
            int row = mt * 16 + m;
            int su = swz(row * 8 + kt * 4 + q) << 3;
            aH[mt] = *(const s8v*)&xsH[su];
            aL[mt] = *(const s8v*)&xsL[su];
        }
        s8v bH[4], bL[4];
#pragma unroll
        for (int nt = 0; nt < 4; ++nt) {
            size_t bi = ((size_t)(kt * 4 + q) * 256 + nb + nt * 16 + m) * 8;
            bH[nt] = *(const s8v*)(wFH + bi);
            bL[nt] = *(const s8v*)(wFL + bi);
        }
#pragma unroll
        for (int mt = 0; mt < 2; ++mt)
#pragma unroll
            for (int nt = 0; nt < 4; ++nt) {
                acc[mt][nt] = MFMA16(aH[mt], bH[nt], acc[mt][nt]);
                acc[mt][nt] = MFMA16(aL[mt], bH[nt], acc[mt][nt]);
                acc[mt][nt] = MFMA16(aH[mt], bL[nt], acc[mt][nt]);
            }
    }

    // Epilogue 1: bias + relu -> hid (bf16 hi/lo, padded rows)
#pragma unroll
    for (int mt = 0; mt < 2; ++mt)
#pragma unroll
        for (int nt = 0; nt < 4; ++nt) {
            int d = nb + nt * 16 + m;
            float bias = conv_b[d];
#pragma unroll
            for (int r = 0; r < 4; ++r) {
                int row = mt * 16 + q * 4 + r;
                float v = fmaxf(acc[mt][nt][r] + bias, 0.0f);
                short h, l; split2(v, h, l);
                hidH[row * HPAD + d] = h;
                hidL[row * HPAD + d] = l;
            }
        }
    __syncthreads();

    // Phase 2: scores GEMM (K=256 over d). Wave wid owns p-range [wid*16, +16).
    const int pb = wid * 16;
    f4v acc2[2];
    acc2[0] = (f4v)0.0f; acc2[1] = (f4v)0.0f;
    for (int kt = 0; kt < 8; ++kt) {
        s8v aH[2], aL[2];
#pragma unroll
        for (int mt = 0; mt < 2; ++mt) {
            int off = (mt * 16 + m) * HPAD + kt * 32 + q * 8;
            aH[mt] = *(const s8v*)&hidH[off];
            aL[mt] = *(const s8v*)&hidL[off];
        }
        size_t bi = ((size_t)(kt * 4 + q) * 64 + pb + m) * 8;
        s8v bH = *(const s8v*)(kFH + bi);
        s8v bL = *(const s8v*)(kFL + bi);
#pragma unroll
        for (int mt = 0; mt < 2; ++mt) {
            acc2[mt] = MFMA16(aH[mt], bH, acc2[mt]);
            acc2[mt] = MFMA16(aL[mt], bH, acc2[mt]);
            acc2[mt] = MFMA16(aH[mt], bL, acc2[mt]);
        }
    }
#pragma unroll
    for (int mt = 0; mt < 2; ++mt)
#pragma unroll
        for (int r = 0; r < 4; ++r) {
            int row = mt * 16 + q * 4 + r;
            float s = fminf(fmaxf(acc2[mt][r], 0.0f), 6.0f) * LOG2E;  // pre-scaled
            scores[((size_t)b * TS + t0 + row) * NPAT + pb + m] = s;
        }
}

// ---- sequential softmax scan: LDS chunk staging + 2 batches interleaved/wave ----
template <int CTRL>
__device__ __forceinline__ float dppadd(float x) {
    int t = __builtin_amdgcn_update_dpp(0, __float_as_int(x), CTRL, 0xf, 0xf, true);
    return x + __int_as_float(t);
}

#define CH 16
#define NCH (TS / CH)   // 64

__launch_bounds__(64)
__global__ void scan_kernel(const float* __restrict__ scores,  // pre-scaled by log2e
                            const float* __restrict__ avg0,
                            float* __restrict__ probs) {
    __shared__ __align__(16) float buf[2][2][CH * 64];   // [dbuf][batch][t*64+p], 16 KB
    const int blk = blockIdx.x;            // 0..127
    const int bA = 2 * blk, bB = 2 * blk + 1;
    const int p = threadIdx.x;

    const float* gA = scores + (size_t)bA * TS * NPAT;
    const float* gB = scores + (size_t)bB * TS * NPAT;
    float* pA = probs + (size_t)bA * TS * NPAT + p;
    float* pB = probs + (size_t)bB * TS * NPAT + p;

    float avgA = avg0[bA * NPAT + p] * LOG2E;   // track avg*log2e
    float avgB = avg0[bB * NPAT + p] * LOG2E;
    const float invc = LOG2E / NPAT;

    // prologue: stage chunk 0 (tile = CH*64 floats = 256 float4, 4 per lane)
    {
        const float4* a4 = (const float4*)gA;
        const float4* b4 = (const float4*)gB;
        float4 ra[4], rb[4];
#pragma unroll
        for (int k = 0; k < 4; ++k) { ra[k] = a4[p + 64 * k]; rb[k] = b4[p + 64 * k]; }
#pragma unroll
        for (int k = 0; k < 4; ++k) {
            *(float4*)&buf[0][0][(p + 64 * k) * 4] = ra[k];
            *(float4*)&buf[0][1][(p + 64 * k) * 4] = rb[k];
        }
    }

    for (int ch = 0; ch < NCH; ++ch) {
        const int cur = ch & 1, nxt = cur ^ 1;
        const bool more = (ch + 1 < NCH);
        // issue next-chunk global loads early (latency hidden behind 16 steps)
        float4 ra[4], rb[4];
        if (more) {
            const float4* a4 = (const float4*)(gA + (size_t)(ch + 1) * CH * 64);
            const float4* b4 = (const float4*)(gB + (size_t)(ch + 1) * CH * 64);
#pragma unroll
            for (int k = 0; k < 4; ++k) { ra[k] = a4[p + 64 * k]; rb[k] = b4[p + 64 * k]; }
        }
        // hoisted LDS reads for the whole chunk (lgkmcnt, compiler schedules fine)
        float sA[CH], sB[CH];
#pragma unroll
        for (int j = 0; j < CH; ++j) {
            sA[j] = buf[cur][0][j * 64 + p];
            sB[j] = buf[cur][1][j * 64 + p];
        }
        // 16 dual softmax steps (two independent dependency chains interleaved)
#pragma unroll
        for (int j = 0; j < CH; ++j) {
            float eA = exp2f(sA[j] - avgA);
            float eB = exp2f(sB[j] - avgB);
            float vA = eA, vB = eB;
            vA = dppadd<0x111>(vA); vB = dppadd<0x111>(vB);   // row_shr:1
            vA = dppadd<0x112>(vA); vB = dppadd<0x112>(vB);   // row_shr:2
            vA = dppadd<0x114>(vA); vB = dppadd<0x114>(vB);   // row_shr:4
            vA = dppadd<0x118>(vA); vB = dppadd<0x118>(vB);   // row_shr:8
            vA = dppadd<0x142>(vA); vB = dppadd<0x142>(vB);   // row_bcast:15
            vA = dppadd<0x143>(vA); vB = dppadd<0x143>(vB);   // row_bcast:31
            float tA = __int_as_float(__builtin_amdgcn_readlane(__float_as_int(vA), 63));
            float tB = __int_as_float(__builtin_amdgcn_readlane(__float_as_int(vB), 63));
            float prAv = eA * __builtin_amdgcn_rcpf(tA);
            float prBv = eB * __builtin_amdgcn_rcpf(tB);
            pA[(size_t)(ch * CH + j) * NPAT] = prAv;
            pB[(size_t)(ch * CH + j) * NPAT] = prBv;
            avgA = __builtin_fmaf(prAv, LOG2E, avgA - invc);
            avgB = __builtin_fmaf(prBv, LOG2E, avgB - invc);
        }
        // stage next chunk into the other buffer
        if (more) {
#pragma unroll
            for (int k = 0; k < 4; ++k) {
                *(float4*)&buf[nxt][0][(p + 64 * k) * 4] = ra[k];
                *(float4*)&buf[nxt][1][(p + 64 * k) * 4] = rb[k];
            }
        }
    }
}

// ---- signal = probs @ shapes (MFMA split-bf16), out = relu(signal - x) ----
__launch_bounds__(256)
__global__ void signal_mfma(const float* __restrict__ probs,
                            const short* __restrict__ sFH, const short* __restrict__ sFL,
                            const float* __restrict__ x,
                            float* __restrict__ out) {
    __shared__ __align__(16) short pH[64 * 72], pL[64 * 72];   // 72 = 64 + 8 pad
    const int b = blockIdx.y, t0 = blockIdx.x * 64;
    const int tid = threadIdx.x;
    const int lane = tid & 63, wid = tid >> 6;
    const int m = lane & 15, q = lane >> 4;

    const float* pbase = probs + ((size_t)b * TS + t0) * NPAT;
    for (int i = tid; i < 64 * 64; i += 256) {
        int r = i >> 6, c = i & 63;
        short h, l; split2(pbase[i], h, l);
        pH[r * 72 + c] = h; pL[r * 72 + c] = l;
    }
    __syncthreads();

    f4v acc[4];
#pragma unroll
    for (int nt = 0; nt < 4; ++nt) acc[nt] = (f4v)0.0f;

#pragma unroll
    for (int kt = 0; kt < 2; ++kt) {
        int off = (wid * 16 + m) * 72 + kt * 32 + q * 8;
        s8v aH = *(const s8v*)&pH[off];
        s8v aL = *(const s8v*)&pL[off];
#pragma unroll
        for (int nt = 0; nt < 4; ++nt) {
            size_t bi = ((size_t)(kt * 4 + q) * 64 + nt * 16 + m) * 8;
            s8v bH = *(const s8v*)(sFH + bi);
            s8v bL = *(const s8v*)(sFL + bi);
            acc[nt] = MFMA16(aH, bH, acc[nt]);
            acc[nt] = MFMA16(aL, bH, acc[nt]);
            acc[nt] = MFMA16(aH, bL, acc[nt]);
        }
    }
#pragma unroll
    for (int nt = 0; nt < 4; ++nt)
#pragma unroll
        for (int r = 0; r < 4; ++r) {
            int row = wid * 16 + q * 4 + r;
            int w = nt * 16 + m;
            size_t gi = (size_t)b * LL + (size_t)(t0 + row) * WINW + w;
            out[gi] = fmaxf(acc[nt][r] - x[gi], 0.0f);
        }
}

extern "C" void kernel_launch(void* const* d_in, const int* in_sizes, int n_in,
                              void* d_out, int out_size, void* d_ws, size_t ws_size,
                              hipStream_t stream) {
    const float* x      = (const float*)d_in[0];
    const float* avg0   = (const float*)d_in[1];
    const float* conv_w = (const float*)d_in[2];
    const float* conv_b = (const float*)d_in[3];
    const float* keys   = (const float*)d_in[4];
    const float* shapes = (const float*)d_in[5];
    float* out = (float*)d_out;

    char* ws = (char*)d_ws;
    size_t o = 0;
    float* scores = (float*)(ws + o); o += (size_t)BB * TS * NPAT * 4;   // 64 MB
    float* probs  = (float*)(ws + o); o += (size_t)BB * TS * NPAT * 4;   // 64 MB
    short* wFH = (short*)(ws + o); o += 8192 * 16;
    short* wFL = (short*)(ws + o); o += 8192 * 16;
    short* kFH = (short*)(ws + o); o += 2048 * 16;
    short* kFL = (short*)(ws + o); o += 2048 * 16;
    short* sFH = (short*)(ws + o); o += 512 * 16;
    short* sFL = (short*)(ws + o); o += 512 * 16;

    prep_wf<<<32, 256, 0, stream>>>(conv_w, wFH, wFL);
    prep_keysf<<<8, 256, 0, stream>>>(keys, kFH, kFL);
    prep_shapesf<<<2, 256, 0, stream>>>(shapes, sFH, sFL);

    scores_mfma<<<dim3(TS / 32, BB), 256, 0, stream>>>(x, wFH, wFL, kFH, kFL, conv_b, scores);
    scan_kernel<<<dim3(BB / 2), 64, 0, stream>>>(scores, avg0, probs);
    signal_mfma<<<dim3(TS / 64, BB), 256, 0, stream>>>(probs, sFH, sFL, x, out);
}

// Round 6
// 448.738 us; speedup vs baseline: 1.4809x; 1.0621x over previous
//
#include <hip/hip_runtime.h>

#define BB 256
#define LL 65536
#define TS 1024
#define HIST 256
#define WINW 64
#define DIM 256
#define NPAT 64

typedef short s8v __attribute__((ext_vector_type(8)));
typedef float f4v __attribute__((ext_vector_type(4)));

#define MFMA16(a, b, c) __builtin_amdgcn_mfma_f32_16x16x32_bf16((a), (b), (c), 0, 0, 0)
#define LOG2E 1.44269504f

// ---- fp32 -> bf16 hi/lo split (combined error ~2^-18 relative) ----
__device__ __forceinline__ short bf16rne(float f) {
    unsigned u = __float_as_uint(f);
    unsigned r = (u + 0x7fffu + ((u >> 16) & 1u)) >> 16;
    return (short)r;
}
__device__ __forceinline__ float bf16tof(short h) {
    return __uint_as_float(((unsigned)(unsigned short)h) << 16);
}
__device__ __forceinline__ void split2(float f, short& hi, short& lo) {
    hi = bf16rne(f);
    lo = bf16rne(f - bf16tof(hi));
}

// ---- merged prep: conv_w / keys / shapes -> hi/lo MFMA B-fragments ----
// blocks 0..31: wF (k=h, n=d); 32..39: kF (k=d, n=p); 40..41: sF (k=p, n=w)
__global__ void prep_all(const float* __restrict__ w, short* __restrict__ wFH,
                         short* __restrict__ wFL,
                         const float* __restrict__ keys, short* __restrict__ kFH,
                         short* __restrict__ kFL,
                         const float* __restrict__ sh, short* __restrict__ sFH,
                         short* __restrict__ sFL) {
    int bid = blockIdx.x;
    s8v hv, lv;
    if (bid < 32) {
        int idx = bid * 256 + threadIdx.x;        // 8192 = 32 qk * 256 d
        int d = idx & 255, qk = idx >> 8;
        int h0 = qk * 8;
#pragma unroll
        for (int j = 0; j < 8; ++j) {
            short h, l; split2(w[d * HIST + h0 + j], h, l);
            hv[j] = h; lv[j] = l;
        }
        *(s8v*)(wFH + (size_t)idx * 8) = hv;
        *(s8v*)(wFL + (size_t)idx * 8) = lv;
    } else if (bid < 40) {
        int idx = (bid - 32) * 256 + threadIdx.x; // 2048 = 32 qk * 64 p
        int p = idx & 63, qk = idx >> 6;
        int d0 = qk * 8;
#pragma unroll
        for (int j = 0; j < 8; ++j) {
            short h, l; split2(keys[(d0 + j) * NPAT + p], h, l);
            hv[j] = h; lv[j] = l;
        }
        *(s8v*)(kFH + (size_t)idx * 8) = hv;
        *(s8v*)(kFL + (size_t)idx * 8) = lv;
    } else {
        int idx = (bid - 40) * 256 + threadIdx.x; // 512 = 8 qk * 64 w
        int ww = idx & 63, qk = idx >> 6;
        int p0 = qk * 8;
#pragma unroll
        for (int j = 0; j < 8; ++j) {
            short h, l; split2(sh[(p0 + j) * WINW + ww], h, l);
            hv[j] = h; lv[j] = l;
        }
        *(s8v*)(sFH + (size_t)idx * 8) = hv;
        *(s8v*)(sFL + (size_t)idx * 8) = lv;
    }
}

#define WELEM 2240           // 31*64 + 256 window elements
#define WUNIT 280            // WELEM/8
#define HPAD 264             // hid row stride (256 + 8)

__device__ __forceinline__ int swz(int u) { return u ^ ((u >> 3) & 7); }

// ---- fused conv + relu + (hid @ keys) + relu6; scoresT[b][p][t] pre-scaled by log2e ----
// block = (32 timesteps, one batch); 256 threads = 4 waves.  [R3-known-good structure]
__launch_bounds__(256, 2)
__global__ void scores_mfma(const float* __restrict__ x,
                            const short* __restrict__ wFH, const short* __restrict__ wFL,
                            const short* __restrict__ kFH, const short* __restrict__ kFL,
                            const float* __restrict__ conv_b,
                            float* __restrict__ scoresT) {
    __shared__ __align__(16) short xsH[WUNIT * 8], xsL[WUNIT * 8];
    __shared__ __align__(16) short hidH[32 * HPAD], hidL[32 * HPAD];

    const int b = blockIdx.y, t0 = blockIdx.x * 32;
    const int tid = threadIdx.x;
    const int lane = tid & 63, wid = tid >> 6;
    const int m = lane & 15, q = lane >> 4;

    const float* xb = x + (size_t)b * LL;
    const int gbase = t0 * WINW - (HIST - 1);
    for (int i = tid; i < WELEM; i += 256) {
        int gi = gbase + i;
        float v = (gi >= 0) ? xb[gi] : 0.0f;
        short h, l; split2(v, h, l);
        int pos = (swz(i >> 3) << 3) | (i & 7);
        xsH[pos] = h; xsL[pos] = l;
    }
    __syncthreads();

    // Phase 1: conv GEMM. Wave wid owns d-range [wid*64, +64).
    const int nb = wid * 64;
    f4v acc[2][4];
#pragma unroll
    for (int mt = 0; mt < 2; ++mt)
#pragma unroll
        for (int nt = 0; nt < 4; ++nt) acc[mt][nt] = (f4v)0.0f;

    for (int kt = 0; kt < 8; ++kt) {
        s8v aH[2], aL[2];
#pragma unroll
        for (int mt = 0; mt < 2; ++mt) {
            int row = mt * 16 + m;
            int su = swz(row * 8 + kt * 4 + q) << 3;
            aH[mt] = *(const s8v*)&xsH[su];
            aL[mt] = *(const s8v*)&xsL[su];
        }
        s8v bH[4], bL[4];
#pragma unroll
        for (int nt = 0; nt < 4; ++nt) {
            size_t bi = ((size_t)(kt * 4 + q) * 256 + nb + nt * 16 + m) * 8;
            bH[nt] = *(const s8v*)(wFH + bi);
            bL[nt] = *(const s8v*)(wFL + bi);
        }
#pragma unroll
        for (int mt = 0; mt < 2; ++mt)
#pragma unroll
            for (int nt = 0; nt < 4; ++nt) {
                acc[mt][nt] = MFMA16(aH[mt], bH[nt], acc[mt][nt]);
                acc[mt][nt] = MFMA16(aL[mt], bH[nt], acc[mt][nt]);
                acc[mt][nt] = MFMA16(aH[mt], bL[nt], acc[mt][nt]);
            }
    }

    // Epilogue 1: bias + relu -> hid (bf16 hi/lo, padded rows)
#pragma unroll
    for (int mt = 0; mt < 2; ++mt)
#pragma unroll
        for (int nt = 0; nt < 4; ++nt) {
            int d = nb + nt * 16 + m;
            float bias = conv_b[d];
#pragma unroll
            for (int r = 0; r < 4; ++r) {
                int row = mt * 16 + q * 4 + r;
                float v = fmaxf(acc[mt][nt][r] + bias, 0.0f);
                short h, l; split2(v, h, l);
                hidH[row * HPAD + d] = h;
                hidL[row * HPAD + d] = l;
            }
        }
    __syncthreads();

    // Phase 2: scores GEMM (K=256 over d). Wave wid owns p-range [wid*16, +16).
    const int pb = wid * 16;
    f4v acc2[2];
    acc2[0] = (f4v)0.0f; acc2[1] = (f4v)0.0f;
    for (int kt = 0; kt < 8; ++kt) {
        s8v aH[2], aL[2];
#pragma unroll
        for (int mt = 0; mt < 2; ++mt) {
            int off = (mt * 16 + m) * HPAD + kt * 32 + q * 8;
            aH[mt] = *(const s8v*)&hidH[off];
            aL[mt] = *(const s8v*)&hidL[off];
        }
        size_t bi = ((size_t)(kt * 4 + q) * 64 + pb + m) * 8;
        s8v bH = *(const s8v*)(kFH + bi);
        s8v bL = *(const s8v*)(kFL + bi);
#pragma unroll
        for (int mt = 0; mt < 2; ++mt) {
            acc2[mt] = MFMA16(aH[mt], bH, acc2[mt]);
            acc2[mt] = MFMA16(aL[mt], bH, acc2[mt]);
            acc2[mt] = MFMA16(aH[mt], bL, acc2[mt]);
        }
    }
    // Transposed epilogue: rows r=0..3 are consecutive t -> one float4 store per mt.
#pragma unroll
    for (int mt = 0; mt < 2; ++mt) {
        float4 st;
        st.x = fminf(fmaxf(acc2[mt][0], 0.0f), 6.0f) * LOG2E;
        st.y = fminf(fmaxf(acc2[mt][1], 0.0f), 6.0f) * LOG2E;
        st.z = fminf(fmaxf(acc2[mt][2], 0.0f), 6.0f) * LOG2E;
        st.w = fminf(fmaxf(acc2[mt][3], 0.0f), 6.0f) * LOG2E;
        *(float4*)&scoresT[((size_t)b * NPAT + pb + m) * TS + t0 + mt * 16 + q * 4] = st;
    }
}

// ---- sequential softmax scan: transposed layout, 4-deep register pipeline, dual batch ----
template <int CTRL>
__device__ __forceinline__ float dppadd(float x) {
    int t = __builtin_amdgcn_update_dpp(0, __float_as_int(x), CTRL, 0xf, 0xf, true);
    return x + __int_as_float(t);
}

__launch_bounds__(64)
__global__ void scan_kernel(const float* __restrict__ scoresT,  // [b][p][t], pre-scaled
                            const float* __restrict__ avg0,
                            float* __restrict__ probsT) {       // [b][p][t]
    const int blk = blockIdx.x;            // 0..127
    const int bA = 2 * blk, bB = 2 * blk + 1;
    const int p = threadIdx.x;

    const float4* sA = (const float4*)(scoresT + ((size_t)bA * NPAT + p) * TS);
    const float4* sB = (const float4*)(scoresT + ((size_t)bB * NPAT + p) * TS);
    float4* qA = (float4*)(probsT + ((size_t)bA * NPAT + p) * TS);
    float4* qB = (float4*)(probsT + ((size_t)bB * NPAT + p) * TS);

    float avgA = avg0[bA * NPAT + p] * LOG2E;   // track avg*log2e
    float avgB = avg0[bB * NPAT + p] * LOG2E;
    const float invc = LOG2E / NPAT;

    // 4-slot compile-time register pipeline (load-use distance ~3 groups)
    float4 bufA[4], bufB[4];
#pragma unroll
    for (int s = 0; s < 4; ++s) { bufA[s] = sA[s]; bufB[s] = sB[s]; }

    for (int base = 0; base < TS / 4; base += 4) {
#pragma unroll
        for (int s = 0; s < 4; ++s) {
            const int g = base + s;
            float4 vA = bufA[s], vB = bufB[s];
            float4 prA, prB;
            float* a = (float*)&vA;  float* bv = (float*)&vB;
            float* pa = (float*)&prA; float* pb = (float*)&prB;
#pragma unroll
            for (int j = 0; j < 4; ++j) {
                float eA = exp2f(a[j] - avgA);
                float eB = exp2f(bv[j] - avgB);
                float wA = eA, wB = eB;
                wA = dppadd<0x111>(wA); wB = dppadd<0x111>(wB);   // row_shr:1
                wA = dppadd<0x112>(wA); wB = dppadd<0x112>(wB);   // row_shr:2
                wA = dppadd<0x114>(wA); wB = dppadd<0x114>(wB);   // row_shr:4
                wA = dppadd<0x118>(wA); wB = dppadd<0x118>(wB);   // row_shr:8
                wA = dppadd<0x142>(wA); wB = dppadd<0x142>(wB);   // row_bcast:15
                wA = dppadd<0x143>(wA); wB = dppadd<0x143>(wB);   // row_bcast:31
                float tA = __int_as_float(__builtin_amdgcn_readlane(__float_as_int(wA), 63));
                float tB = __int_as_float(__builtin_amdgcn_readlane(__float_as_int(wB), 63));
                float prAv = eA * __builtin_amdgcn_rcpf(tA);
                float prBv = eB * __builtin_amdgcn_rcpf(tB);
                pa[j] = prAv; pb[j] = prBv;
                avgA = __builtin_fmaf(prAv, LOG2E, avgA - invc);
                avgB = __builtin_fmaf(prBv, LOG2E, avgB - invc);
            }
            if (g + 4 < TS / 4) {            // refill slot (static index, deep in flight)
                bufA[s] = sA[g + 4];
                bufB[s] = sB[g + 4];
            }
            qA[g] = prA;                     // contiguous 16 B store per group
            qB[g] = prB;
        }
    }
}

// ---- signal = probs @ shapes (MFMA split-bf16), out = relu(signal - x) ----
__launch_bounds__(256)
__global__ void signal_mfma(const float* __restrict__ probsT,   // [b][p][t]
                            const short* __restrict__ sFH, const short* __restrict__ sFL,
                            const float* __restrict__ x,
                            float* __restrict__ out) {
    __shared__ __align__(16) short pH[64 * 72], pL[64 * 72];   // [t][p], 72 = 64+8 pad
    const int b = blockIdx.y, t0 = blockIdx.x * 64;
    const int tid = threadIdx.x;
    const int lane = tid & 63, wid = tid >> 6;
    const int m = lane & 15, q = lane >> 4;

    // Stage 64 t x 64 p tile from transposed probs: lane = p, 4 float4 along t.
    {
        const int pl = tid & 63, ck = tid >> 6;     // ck = t-chunk 0..3
        const float* src = probsT + ((size_t)b * NPAT + pl) * TS + t0 + ck * 16;
#pragma unroll
        for (int k = 0; k < 4; ++k) {
            float4 v = *(const float4*)(src + k * 4);
            float* vp = (float*)&v;
#pragma unroll
            for (int j = 0; j < 4; ++j) {
                short h, l; split2(vp[j], h, l);
                int t = ck * 16 + k * 4 + j;
                pH[t * 72 + pl] = h;
                pL[t * 72 + pl] = l;
            }
        }
    }
    __syncthreads();

    f4v acc[4];
#pragma unroll
    for (int nt = 0; nt < 4; ++nt) acc[nt] = (f4v)0.0f;

#pragma unroll
    for (int kt = 0; kt < 2; ++kt) {
        int off = (wid * 16 + m) * 72 + kt * 32 + q * 8;
        s8v aH = *(const s8v*)&pH[off];
        s8v aL = *(const s8v*)&pL[off];
#pragma unroll
        for (int nt = 0; nt < 4; ++nt) {
            size_t bi = ((size_t)(kt * 4 + q) * 64 + nt * 16 + m) * 8;
            s8v bH = *(const s8v*)(sFH + bi);
            s8v bL = *(const s8v*)(sFL + bi);
            acc[nt] = MFMA16(aH, bH, acc[nt]);
            acc[nt] = MFMA16(aL, bH, acc[nt]);
            acc[nt] = MFMA16(aH, bL, acc[nt]);
        }
    }
#pragma unroll
    for (int nt = 0; nt < 4; ++nt)
#pragma unroll
        for (int r = 0; r < 4; ++r) {
            int row = wid * 16 + q * 4 + r;
            int w = nt * 16 + m;
            size_t gi = (size_t)b * LL + (size_t)(t0 + row) * WINW + w;
            out[gi] = fmaxf(acc[nt][r] - x[gi], 0.0f);
        }
}

extern "C" void kernel_launch(void* const* d_in, const int* in_sizes, int n_in,
                              void* d_out, int out_size, void* d_ws, size_t ws_size,
                              hipStream_t stream) {
    const float* x      = (const float*)d_in[0];
    const float* avg0   = (const float*)d_in[1];
    const float* conv_w = (const float*)d_in[2];
    const float* conv_b = (const float*)d_in[3];
    const float* keys   = (const float*)d_in[4];
    const float* shapes = (const float*)d_in[5];
    float* out = (float*)d_out;

    char* ws = (char*)d_ws;
    size_t o = 0;
    float* scoresT = (float*)(ws + o); o += (size_t)BB * TS * NPAT * 4;   // 64 MB
    float* probsT  = (float*)(ws + o); o += (size_t)BB * TS * NPAT * 4;   // 64 MB
    short* wFH = (short*)(ws + o); o += 8192 * 16;
    short* wFL = (short*)(ws + o); o += 8192 * 16;
    short* kFH = (short*)(ws + o); o += 2048 * 16;
    short* kFL = (short*)(ws + o); o += 2048 * 16;
    short* sFH = (short*)(ws + o); o += 512 * 16;
    short* sFL = (short*)(ws + o); o += 512 * 16;

    prep_all<<<42, 256, 0, stream>>>(conv_w, wFH, wFL, keys, kFH, kFL, shapes, sFH, sFL);
    scores_mfma<<<dim3(TS / 32, BB), 256, 0, stream>>>(x, wFH, wFL, kFH, kFL, conv_b, scoresT);
    scan_kernel<<<dim3(BB / 2), 64, 0, stream>>>(scoresT, avg0, probsT);
    signal_mfma<<<dim3(TS / 64, BB), 256, 0, stream>>>(probsT, sFH, sFL, x, out);
}